// Round 4
// baseline (478.872 us; speedup 1.0000x reference)
//
#include <hip/hip_runtime.h>
#include <hip/hip_cooperative_groups.h>

// FeatureExtractor: out = concat([x, |ifft2(low)|/max, |ifft2(high)|/max], axis=1)
// x: (32,3,512,512) fp32. Mask keeps 45 freq bins (|ky|,|kx|<=3, ky^2+kx^2<16).
// Low-pass signal s is REAL (symmetric mask, real input); hp = |x - s|.
// Pipeline: K1 row-DFT -> K2 col-DFT + per-x table Rtab -> K34 (cooperative:
// maxes -> grid.sync -> normalized write, x held in registers across the sync).

#define NN 512
#define IMGS 96
constexpr float TWOPI_N = 6.2831853071795864769f / 512.0f;
constexpr float INV_N2  = 1.0f / (512.0f * 512.0f);

typedef float f4v __attribute__((ext_vector_type(4)));

// workspace layout (bytes)
#define G_OFF   0                              // 96*512*8 floats = 1,572,864 B
#define R_OFF   (96 * 512 * 8 * 4)             // Rtab: 96*512*8 floats = 1,572,864 B
#define MAX_OFF (R_OFF + 96 * 512 * 8 * 4)     // 2 uints
#define WS_NEEDED (MAX_OFF + 8)

// ---------------- K1: per-row DFT at kx=0..3 (4 rows/wave, 16 lanes/row) ----
__global__ __launch_bounds__(256) void k1_rowfft(const float* __restrict__ x,
                                                 float* __restrict__ G,
                                                 unsigned int* __restrict__ maxes) {
  const int tid = threadIdx.x;
  if (blockIdx.x == 0 && blockIdx.y == 0 && tid == 0) {
    maxes[0] = 0u; maxes[1] = 0u;   // fold memset into K1 (K34 runs later in stream)
  }
  const int img = blockIdx.y;
  const int row = blockIdx.x * 16 + ((tid >> 6) << 2) + ((tid & 63) >> 4);
  const int l16 = tid & 15;
  const float* xr = x + (((size_t)img) << 18) + row * NN;

  float gr0 = 0.f, gr1 = 0.f, gi1 = 0.f, gr2 = 0.f, gi2 = 0.f, gr3 = 0.f, gi3 = 0.f;
  const float cd  = 0.99992470183914454f;    // cos(2pi/512)
  const float sd  = 0.012271538285719925f;   // sin(2pi/512)
  const float r45 = 0.70710678118654752f;    // cos(pi/4) = sin(pi/4), EXACT rotation/iter
  float c, s;
  __sincosf(TWOPI_N * (float)(l16 * 4), &s, &c);
  #pragma unroll
  for (int it = 0; it < 8; ++it) {
    const float4 xv = *reinterpret_cast<const float4*>(xr + it * 64 + l16 * 4);
    const float xe[4] = {xv.x, xv.y, xv.z, xv.w};
    float cc = c, ss = s;
    #pragma unroll
    for (int j = 0; j < 4; ++j) {
      const float c2 = cc * cc - ss * ss, s2 = 2.f * cc * ss;
      const float c3 = cc * c2 - ss * s2, s3 = ss * c2 + cc * s2;
      const float xx = xe[j];
      gr0 += xx;
      gr1 = fmaf(xx, cc, gr1);  gi1 = fmaf(-xx, ss, gi1);   // e^{-i*1*theta}
      gr2 = fmaf(xx, c2, gr2);  gi2 = fmaf(-xx, s2, gi2);
      gr3 = fmaf(xx, c3, gr3);  gi3 = fmaf(-xx, s3, gi3);
      const float cn = cc * cd - ss * sd;
      const float sn = ss * cd + cc * sd;
      cc = cn; ss = sn;
    }
    const float cN = r45 * (c - s);   // advance base by 64 columns = pi/4, exact
    const float sN = r45 * (c + s);
    c = cN; s = sN;
  }
  #pragma unroll
  for (int off = 8; off; off >>= 1) {
    gr0 += __shfl_down(gr0, off);
    gr1 += __shfl_down(gr1, off); gi1 += __shfl_down(gi1, off);
    gr2 += __shfl_down(gr2, off); gi2 += __shfl_down(gi2, off);
    gr3 += __shfl_down(gr3, off); gi3 += __shfl_down(gi3, off);
  }
  if (l16 == 0) {
    float* g = G + (size_t)(img * 512 + row) * 8;
    *reinterpret_cast<float4*>(g)     = make_float4(gr0, 0.f, gr1, gi1);
    *reinterpret_cast<float4*>(g + 4) = make_float4(gr2, gi2, gr3, gi3);
  }
}

// ---------------- K2: column DFT G -> F (LDS) -> per-x table Rtab ------------
__global__ __launch_bounds__(256) void k2_colfft(const float* __restrict__ G,
                                                 float* __restrict__ Rtab) {
  const int img = blockIdx.x;
  const int tid = threadIdx.x;
  float Fr[28], Fi[28];
  #pragma unroll
  for (int f = 0; f < 28; ++f) { Fr[f] = 0.f; Fi[f] = 0.f; }

  #pragma unroll
  for (int half = 0; half < 2; ++half) {
    const int u = half * 256 + tid;
    const float* g = G + (size_t)(img * 512 + u) * 8;
    const float4 ga = *reinterpret_cast<const float4*>(g);
    const float4 gb = *reinterpret_cast<const float4*>(g + 4);
    const float Gr[4] = {ga.x, ga.z, gb.x, gb.z};
    const float Gi[4] = {0.f,  ga.w, gb.y, gb.w};
    float cu, su;
    __sincosf(TWOPI_N * (float)u, &su, &cu);
    float pc[4], ps[4];
    pc[0] = 1.f; ps[0] = 0.f;
    pc[1] = cu;  ps[1] = su;
    pc[2] = cu * cu - su * su; ps[2] = 2.f * cu * su;
    pc[3] = pc[1] * pc[2] - ps[1] * ps[2];
    ps[3] = ps[1] * pc[2] + pc[1] * ps[2];
    #pragma unroll
    for (int ky = 0; ky < 4; ++ky) {
      const float c = pc[ky], s = ps[ky];   // e^{-i ky u th} = (c, -s)
      #pragma unroll
      for (int kxs = 0; kxs < 7; ++kxs) {
        const int a = (kxs < 3) ? (3 - kxs) : (kxs - 3);
        const float gr = Gr[a];
        const float gi = (kxs < 3) ? -Gi[a] : Gi[a];   // G[u,-k] = conj(G[u,k])
        const int f = ky * 7 + kxs;
        Fr[f] += gr * c + gi * s;
        Fi[f] += gi * c - gr * s;
      }
    }
  }
  __shared__ float sm[4][56];
  __shared__ float Ff[56];
  const int lane = tid & 63;
  const int wv = tid >> 6;
  #pragma unroll
  for (int f = 0; f < 28; ++f) {
    float fr = Fr[f], fi = Fi[f];
    #pragma unroll
    for (int off = 32; off; off >>= 1) {
      fr += __shfl_down(fr, off);
      fi += __shfl_down(fi, off);
    }
    if (lane == 0) { sm[wv][f * 2] = fr; sm[wv][f * 2 + 1] = fi; }
  }
  __syncthreads();
  if (tid < 56) {
    Ff[tid] = sm[0][tid] + sm[1][tid] + sm[2][tid] + sm[3][tid];
  }
  __syncthreads();

  // per-x reconstruction table: Rtab[x][8] = (R0, 2R1r, 2R1i, 2R2r, 2R2i, 2R3r, 2R3i, 0)/N^2
  float fr[28], fi[28];
  #pragma unroll
  for (int f = 0; f < 28; ++f) { fr[f] = Ff[2 * f]; fi[f] = Ff[2 * f + 1]; }
  #pragma unroll
  for (int half = 0; half < 2; ++half) {
    const int xx = half * 256 + tid;
    float c1, s1;
    __sincosf(TWOPI_N * (float)xx, &s1, &c1);
    const float c2 = c1 * c1 - s1 * s1, s2 = 2.f * c1 * s1;
    const float c3 = c1 * c2 - s1 * s2, s3 = s1 * c2 + c1 * s2;
    const float pc[4] = {1.f, c1, c2, c3};
    const float ps[4] = {0.f, s1, s2, s3};
    float Rr[4], Ri[4];
    #pragma unroll
    for (int ky = 0; ky < 4; ++ky) {
      float rr = 0.f, ri = 0.f;
      #pragma unroll
      for (int kxs = 0; kxs < 7; ++kxs) {
        if (ky == 3 && (kxs == 0 || kxs == 6)) continue;  // 9+9 >= 16 excluded
        const int a = (kxs < 3) ? (3 - kxs) : (kxs - 3);
        const float ec = pc[a];
        const float es = (kxs < 3) ? -ps[a] : ps[a];      // e^{+i kx x th}
        const int f = ky * 7 + kxs;
        rr += fr[f] * ec - fi[f] * es;
        ri += fr[f] * es + fi[f] * ec;
      }
      Rr[ky] = rr; Ri[ky] = ri;
    }
    float* o = Rtab + (size_t)(img * 512 + xx) * 8;
    const float k2s = 2.f * INV_N2;
    *reinterpret_cast<float4*>(o) =
        make_float4(Rr[0] * INV_N2, Rr[1] * k2s, Ri[1] * k2s, Rr[2] * k2s);
    *reinterpret_cast<float4*>(o + 4) =
        make_float4(Ri[2] * k2s, Rr[3] * k2s, Ri[3] * k2s, 0.f);
  }
}

// ---------------- shared per-block prologue for K3/K4/K34 ----------------
__device__ __forceinline__ void load_ctx(const float* __restrict__ Rtab, int img,
                                         int xi, int ybase, int tid,
                                         float (*yt)[6], float4 Ra[4], float4 Rb[4]) {
  if (tid < 32) {
    const int y = ybase + tid;
    float c1, s1;
    __sincosf(TWOPI_N * (float)y, &s1, &c1);
    const float c2 = c1 * c1 - s1 * s1, s2 = 2.f * c1 * s1;
    const float c3 = c1 * c2 - s1 * s2, s3 = s1 * c2 + c1 * s2;
    yt[tid][0] = c1; yt[tid][1] = s1;
    yt[tid][2] = c2; yt[tid][3] = s2;
    yt[tid][4] = c3; yt[tid][5] = s3;
  }
  const float* rt = Rtab + (size_t)(img * 512 + xi) * 8;
  #pragma unroll
  for (int j = 0; j < 4; ++j) {
    Ra[j] = *reinterpret_cast<const float4*>(rt + j * 8);
    Rb[j] = *reinterpret_cast<const float4*>(rt + j * 8 + 4);
  }
  __syncthreads();
}

__device__ __forceinline__ float recon(const float4& Ra, const float4& Rb,
                                       const float* yy) {
  float S = Ra.x;
  S = fmaf(Ra.y,  yy[0], S); S = fmaf(-Ra.z, yy[1], S);
  S = fmaf(Ra.w,  yy[2], S); S = fmaf(-Rb.x, yy[3], S);
  S = fmaf(Rb.y,  yy[4], S); S = fmaf(-Rb.z, yy[5], S);
  return S;
}

// ---------------- K34 (cooperative): maxes -> grid.sync -> write -----------
// x held in registers (16 x float4) across the sync; one x read total.
// Grid is EXACTLY 16x96 = 1536 blocks = 6 blocks/CU * 4 waves = 24 waves/CU.
__global__ __launch_bounds__(256, 6) void k34_fused(const float* __restrict__ x,
    const float* __restrict__ Rtab, unsigned int* __restrict__ maxes,
    float* __restrict__ out) {
  const int img = blockIdx.y;
  const int b = img / 3, c = img - b * 3;
  const int tid = threadIdx.x;
  const int xi = (tid & 127) * 4;
  const int p = tid >> 7;
  const int ybase = blockIdx.x * 32;
  __shared__ float yt[32][6];
  float4 Ra[4], Rb[4];
  load_ctx(Rtab, img, xi, ybase, tid, yt, Ra, Rb);

  const float* xim = x + (((size_t)img) << 18);
  float4 xv[16];
  float mlp = 0.f, mhp = 0.f;
  #pragma unroll
  for (int it = 0; it < 16; ++it) {
    const int yy = it * 2 + p;
    const int y = ybase + yy;
    xv[it] = *reinterpret_cast<const float4*>(xim + y * NN + xi);
    float yv[6];
    #pragma unroll
    for (int q = 0; q < 6; ++q) yv[q] = yt[yy][q];
    const float xe[4] = {xv[it].x, xv[it].y, xv[it].z, xv[it].w};
    #pragma unroll
    for (int j = 0; j < 4; ++j) {
      const float sig = recon(Ra[j], Rb[j], yv);
      mlp = fmaxf(mlp, fabsf(sig));
      mhp = fmaxf(mhp, fabsf(xe[j] - sig));
    }
  }
  #pragma unroll
  for (int off = 32; off; off >>= 1) {
    mlp = fmaxf(mlp, __shfl_down(mlp, off));
    mhp = fmaxf(mhp, __shfl_down(mhp, off));
  }
  __shared__ float sm[8];
  const int lane = tid & 63, wv = tid >> 6;
  if (lane == 0) { sm[wv * 2] = mlp; sm[wv * 2 + 1] = mhp; }
  __syncthreads();
  if (tid == 0) {
    const float a = fmaxf(fmaxf(sm[0], sm[2]), fmaxf(sm[4], sm[6]));
    const float bb = fmaxf(fmaxf(sm[1], sm[3]), fmaxf(sm[5], sm[7]));
    atomicMax(&maxes[0], __float_as_uint(a));   // nonneg floats: bit order == value order
    atomicMax(&maxes[1], __float_as_uint(bb));
  }
  __threadfence();
  cooperative_groups::this_grid().sync();

  const float inv_lp = 1.f / __uint_as_float(
      __hip_atomic_load(&maxes[0], __ATOMIC_RELAXED, __HIP_MEMORY_SCOPE_AGENT));
  const float inv_hp = 1.f / __uint_as_float(
      __hip_atomic_load(&maxes[1], __ATOMIC_RELAXED, __HIP_MEMORY_SCOPE_AGENT));
  float* o0 = out + (((size_t)(b * 9 + c)) << 18);
  float* o1 = out + (((size_t)(b * 9 + 3 + c)) << 18);
  float* o2 = out + (((size_t)(b * 9 + 6 + c)) << 18);
  #pragma unroll
  for (int it = 0; it < 16; ++it) {
    const int yy = it * 2 + p;
    const int y = ybase + yy;
    float yv[6];
    #pragma unroll
    for (int q = 0; q < 6; ++q) yv[q] = yt[yy][q];
    const float xe[4] = {xv[it].x, xv[it].y, xv[it].z, xv[it].w};
    f4v lpv, hpv, xvv;
    #pragma unroll
    for (int j = 0; j < 4; ++j) {
      const float sig = recon(Ra[j], Rb[j], yv);
      lpv[j] = fabsf(sig) * inv_lp;
      hpv[j] = fabsf(xe[j] - sig) * inv_hp;
      xvv[j] = xe[j];
    }
    const int o = y * NN + xi;
    __builtin_nontemporal_store(xvv, reinterpret_cast<f4v*>(o0 + o));
    __builtin_nontemporal_store(lpv, reinterpret_cast<f4v*>(o1 + o));
    __builtin_nontemporal_store(hpv, reinterpret_cast<f4v*>(o2 + o));
  }
}

// ---------------- fallback pair (used only if cooperative launch fails) -----
__global__ __launch_bounds__(256) void k3_maxes(const float* __restrict__ x,
    const float* __restrict__ Rtab, unsigned int* __restrict__ maxes) {
  const int img = blockIdx.y;
  const int tid = threadIdx.x;
  const int xi = (tid & 127) * 4;
  const int p = tid >> 7;
  const int ybase = blockIdx.x * 32;
  __shared__ float yt[32][6];
  float4 Ra[4], Rb[4];
  load_ctx(Rtab, img, xi, ybase, tid, yt, Ra, Rb);
  const float* xim = x + (((size_t)img) << 18);
  float mlp = 0.f, mhp = 0.f;
  for (int it = 0; it < 16; ++it) {
    const int yy = it * 2 + p;
    const int y = ybase + yy;
    float yv[6];
    #pragma unroll
    for (int q = 0; q < 6; ++q) yv[q] = yt[yy][q];
    const float4 xv = *reinterpret_cast<const float4*>(xim + y * NN + xi);
    const float xe[4] = {xv.x, xv.y, xv.z, xv.w};
    #pragma unroll
    for (int j = 0; j < 4; ++j) {
      const float sig = recon(Ra[j], Rb[j], yv);
      mlp = fmaxf(mlp, fabsf(sig));
      mhp = fmaxf(mhp, fabsf(xe[j] - sig));
    }
  }
  #pragma unroll
  for (int off = 32; off; off >>= 1) {
    mlp = fmaxf(mlp, __shfl_down(mlp, off));
    mhp = fmaxf(mhp, __shfl_down(mhp, off));
  }
  __shared__ float sm[8];
  const int lane = tid & 63, wv = tid >> 6;
  if (lane == 0) { sm[wv * 2] = mlp; sm[wv * 2 + 1] = mhp; }
  __syncthreads();
  if (tid == 0) {
    const float a = fmaxf(fmaxf(sm[0], sm[2]), fmaxf(sm[4], sm[6]));
    const float bb = fmaxf(fmaxf(sm[1], sm[3]), fmaxf(sm[5], sm[7]));
    atomicMax(&maxes[0], __float_as_uint(a));
    atomicMax(&maxes[1], __float_as_uint(bb));
  }
}

__global__ __launch_bounds__(256) void k4_write(const float* __restrict__ x,
    const float* __restrict__ Rtab, const unsigned int* __restrict__ maxes,
    float* __restrict__ out) {
  const int img = blockIdx.y;
  const int b = img / 3, c = img - b * 3;
  const int tid = threadIdx.x;
  const int xi = (tid & 127) * 4;
  const int p = tid >> 7;
  const int ybase = blockIdx.x * 32;
  __shared__ float yt[32][6];
  float4 Ra[4], Rb[4];
  load_ctx(Rtab, img, xi, ybase, tid, yt, Ra, Rb);
  const float inv_lp = 1.f / __uint_as_float(maxes[0]);
  const float inv_hp = 1.f / __uint_as_float(maxes[1]);
  const float* xim = x + (((size_t)img) << 18);
  float* o0 = out + (((size_t)(b * 9 + c)) << 18);
  float* o1 = out + (((size_t)(b * 9 + 3 + c)) << 18);
  float* o2 = out + (((size_t)(b * 9 + 6 + c)) << 18);
  for (int it = 0; it < 16; ++it) {
    const int yy = it * 2 + p;
    const int y = ybase + yy;
    float yv[6];
    #pragma unroll
    for (int q = 0; q < 6; ++q) yv[q] = yt[yy][q];
    const float4 xv = *reinterpret_cast<const float4*>(xim + y * NN + xi);
    const float xe[4] = {xv.x, xv.y, xv.z, xv.w};
    f4v lpv, hpv, xvv;
    #pragma unroll
    for (int j = 0; j < 4; ++j) {
      const float sig = recon(Ra[j], Rb[j], yv);
      lpv[j] = fabsf(sig) * inv_lp;
      hpv[j] = fabsf(xe[j] - sig) * inv_hp;
      xvv[j] = xe[j];
    }
    const int o = y * NN + xi;
    __builtin_nontemporal_store(xvv, reinterpret_cast<f4v*>(o0 + o));
    __builtin_nontemporal_store(lpv, reinterpret_cast<f4v*>(o1 + o));
    __builtin_nontemporal_store(hpv, reinterpret_cast<f4v*>(o2 + o));
  }
}

extern "C" void kernel_launch(void* const* d_in, const int* in_sizes, int n_in,
                              void* d_out, int out_size, void* d_ws, size_t ws_size,
                              hipStream_t stream) {
  if (ws_size < (size_t)WS_NEEDED) return;  // loud failure instead of corruption
  const float* x = (const float*)d_in[0];
  float* out = (float*)d_out;
  char* ws = (char*)d_ws;
  float* G = (float*)(ws + G_OFF);
  float* Rtab = (float*)(ws + R_OFF);
  unsigned int* maxes = (unsigned int*)(ws + MAX_OFF);

  k1_rowfft<<<dim3(32, IMGS), 256, 0, stream>>>(x, G, maxes);
  k2_colfft<<<dim3(IMGS), 256, 0, stream>>>(G, Rtab);

  void* args[] = {(void*)&x, (void*)&Rtab, (void*)&maxes, (void*)&out};
  hipError_t e = hipLaunchCooperativeKernel((const void*)k34_fused,
                                            dim3(16, IMGS), dim3(256),
                                            args, 0, stream);
  if (e != hipSuccess) {
    // fallback: proven two-kernel path (same numerics)
    k3_maxes<<<dim3(16, IMGS), 256, 0, stream>>>(x, Rtab, maxes);
    k4_write<<<dim3(16, IMGS), 256, 0, stream>>>(x, Rtab, maxes, out);
  }
}

// Round 5
// 203.353 us; speedup vs baseline: 2.3549x; 2.3549x over previous
//
#include <hip/hip_runtime.h>
#include <hip/hip_cooperative_groups.h>

// FeatureExtractor: out = concat([x, |ifft2(low)|/max, |ifft2(high)|/max], axis=1)
// x: (32,3,512,512) fp32. Mask keeps 45 freq bins (|ky|,|kx|<=3, ky^2+kx^2<16).
// Low-pass signal s is REAL (symmetric mask, real input); hp = |x - s|.
// Pipeline: K1 row-DFT -> K2 col-DFT + per-x table Rtab -> K34 cooperative
// (phase A maxes -> grid.sync -> phase B write; x re-read from L3, NO reg carry
//  -- R4's reg-carry at forced 6 blocks/CU spilled to scratch: VGPR=40, +200MB).

#define NN 512
#define IMGS 96
constexpr float TWOPI_N = 6.2831853071795864769f / 512.0f;
constexpr float INV_N2  = 1.0f / (512.0f * 512.0f);

typedef float f4v __attribute__((ext_vector_type(4)));

// workspace layout (bytes)
#define G_OFF   0                              // 96*512*8 floats = 1,572,864 B
#define R_OFF   (96 * 512 * 8 * 4)             // Rtab: 96*512*8 floats = 1,572,864 B
#define MAX_OFF (R_OFF + 96 * 512 * 8 * 4)     // 2 uints
#define WS_NEEDED (MAX_OFF + 8)

// ---------------- K1: per-row DFT at kx=0..3 (4 rows/wave, 16 lanes/row) ----
__global__ __launch_bounds__(256) void k1_rowfft(const float* __restrict__ x,
                                                 float* __restrict__ G,
                                                 unsigned int* __restrict__ maxes) {
  const int tid = threadIdx.x;
  if (blockIdx.x == 0 && blockIdx.y == 0 && tid == 0) {
    maxes[0] = 0u; maxes[1] = 0u;   // fold memset into K1 (K34 runs later in stream)
  }
  const int img = blockIdx.y;
  const int row = blockIdx.x * 16 + ((tid >> 6) << 2) + ((tid & 63) >> 4);
  const int l16 = tid & 15;
  const float* xr = x + (((size_t)img) << 18) + row * NN;

  float gr0 = 0.f, gr1 = 0.f, gi1 = 0.f, gr2 = 0.f, gi2 = 0.f, gr3 = 0.f, gi3 = 0.f;
  const float cd  = 0.99992470183914454f;    // cos(2pi/512)
  const float sd  = 0.012271538285719925f;   // sin(2pi/512)
  const float r45 = 0.70710678118654752f;    // cos(pi/4) = sin(pi/4), EXACT rotation/iter
  float c, s;
  __sincosf(TWOPI_N * (float)(l16 * 4), &s, &c);
  #pragma unroll
  for (int it = 0; it < 8; ++it) {
    const float4 xv = *reinterpret_cast<const float4*>(xr + it * 64 + l16 * 4);
    const float xe[4] = {xv.x, xv.y, xv.z, xv.w};
    float cc = c, ss = s;
    #pragma unroll
    for (int j = 0; j < 4; ++j) {
      const float c2 = cc * cc - ss * ss, s2 = 2.f * cc * ss;
      const float c3 = cc * c2 - ss * s2, s3 = ss * c2 + cc * s2;
      const float xx = xe[j];
      gr0 += xx;
      gr1 = fmaf(xx, cc, gr1);  gi1 = fmaf(-xx, ss, gi1);   // e^{-i*1*theta}
      gr2 = fmaf(xx, c2, gr2);  gi2 = fmaf(-xx, s2, gi2);
      gr3 = fmaf(xx, c3, gr3);  gi3 = fmaf(-xx, s3, gi3);
      const float cn = cc * cd - ss * sd;
      const float sn = ss * cd + cc * sd;
      cc = cn; ss = sn;
    }
    const float cN = r45 * (c - s);   // advance base by 64 columns = pi/4, exact
    const float sN = r45 * (c + s);
    c = cN; s = sN;
  }
  #pragma unroll
  for (int off = 8; off; off >>= 1) {
    gr0 += __shfl_down(gr0, off);
    gr1 += __shfl_down(gr1, off); gi1 += __shfl_down(gi1, off);
    gr2 += __shfl_down(gr2, off); gi2 += __shfl_down(gi2, off);
    gr3 += __shfl_down(gr3, off); gi3 += __shfl_down(gi3, off);
  }
  if (l16 == 0) {
    float* g = G + (size_t)(img * 512 + row) * 8;
    *reinterpret_cast<float4*>(g)     = make_float4(gr0, 0.f, gr1, gi1);
    *reinterpret_cast<float4*>(g + 4) = make_float4(gr2, gi2, gr3, gi3);
  }
}

// ---------------- K2: column DFT G -> F (LDS) -> per-x table Rtab ------------
__global__ __launch_bounds__(256) void k2_colfft(const float* __restrict__ G,
                                                 float* __restrict__ Rtab) {
  const int img = blockIdx.x;
  const int tid = threadIdx.x;
  float Fr[28], Fi[28];
  #pragma unroll
  for (int f = 0; f < 28; ++f) { Fr[f] = 0.f; Fi[f] = 0.f; }

  #pragma unroll
  for (int half = 0; half < 2; ++half) {
    const int u = half * 256 + tid;
    const float* g = G + (size_t)(img * 512 + u) * 8;
    const float4 ga = *reinterpret_cast<const float4*>(g);
    const float4 gb = *reinterpret_cast<const float4*>(g + 4);
    const float Gr[4] = {ga.x, ga.z, gb.x, gb.z};
    const float Gi[4] = {0.f,  ga.w, gb.y, gb.w};
    float cu, su;
    __sincosf(TWOPI_N * (float)u, &su, &cu);
    float pc[4], ps[4];
    pc[0] = 1.f; ps[0] = 0.f;
    pc[1] = cu;  ps[1] = su;
    pc[2] = cu * cu - su * su; ps[2] = 2.f * cu * su;
    pc[3] = pc[1] * pc[2] - ps[1] * ps[2];
    ps[3] = ps[1] * pc[2] + pc[1] * ps[2];
    #pragma unroll
    for (int ky = 0; ky < 4; ++ky) {
      const float c = pc[ky], s = ps[ky];   // e^{-i ky u th} = (c, -s)
      #pragma unroll
      for (int kxs = 0; kxs < 7; ++kxs) {
        const int a = (kxs < 3) ? (3 - kxs) : (kxs - 3);
        const float gr = Gr[a];
        const float gi = (kxs < 3) ? -Gi[a] : Gi[a];   // G[u,-k] = conj(G[u,k])
        const int f = ky * 7 + kxs;
        Fr[f] += gr * c + gi * s;
        Fi[f] += gi * c - gr * s;
      }
    }
  }
  __shared__ float sm[4][56];
  __shared__ float Ff[56];
  const int lane = tid & 63;
  const int wv = tid >> 6;
  #pragma unroll
  for (int f = 0; f < 28; ++f) {
    float fr = Fr[f], fi = Fi[f];
    #pragma unroll
    for (int off = 32; off; off >>= 1) {
      fr += __shfl_down(fr, off);
      fi += __shfl_down(fi, off);
    }
    if (lane == 0) { sm[wv][f * 2] = fr; sm[wv][f * 2 + 1] = fi; }
  }
  __syncthreads();
  if (tid < 56) {
    Ff[tid] = sm[0][tid] + sm[1][tid] + sm[2][tid] + sm[3][tid];
  }
  __syncthreads();

  // per-x reconstruction table: Rtab[x][8] = (R0, 2R1r, 2R1i, 2R2r, 2R2i, 2R3r, 2R3i, 0)/N^2
  float fr[28], fi[28];
  #pragma unroll
  for (int f = 0; f < 28; ++f) { fr[f] = Ff[2 * f]; fi[f] = Ff[2 * f + 1]; }
  #pragma unroll
  for (int half = 0; half < 2; ++half) {
    const int xx = half * 256 + tid;
    float c1, s1;
    __sincosf(TWOPI_N * (float)xx, &s1, &c1);
    const float c2 = c1 * c1 - s1 * s1, s2 = 2.f * c1 * s1;
    const float c3 = c1 * c2 - s1 * s2, s3 = s1 * c2 + c1 * s2;
    const float pc[4] = {1.f, c1, c2, c3};
    const float ps[4] = {0.f, s1, s2, s3};
    float Rr[4], Ri[4];
    #pragma unroll
    for (int ky = 0; ky < 4; ++ky) {
      float rr = 0.f, ri = 0.f;
      #pragma unroll
      for (int kxs = 0; kxs < 7; ++kxs) {
        if (ky == 3 && (kxs == 0 || kxs == 6)) continue;  // 9+9 >= 16 excluded
        const int a = (kxs < 3) ? (3 - kxs) : (kxs - 3);
        const float ec = pc[a];
        const float es = (kxs < 3) ? -ps[a] : ps[a];      // e^{+i kx x th}
        const int f = ky * 7 + kxs;
        rr += fr[f] * ec - fi[f] * es;
        ri += fr[f] * es + fi[f] * ec;
      }
      Rr[ky] = rr; Ri[ky] = ri;
    }
    float* o = Rtab + (size_t)(img * 512 + xx) * 8;
    const float k2s = 2.f * INV_N2;
    *reinterpret_cast<float4*>(o) =
        make_float4(Rr[0] * INV_N2, Rr[1] * k2s, Ri[1] * k2s, Rr[2] * k2s);
    *reinterpret_cast<float4*>(o + 4) =
        make_float4(Ri[2] * k2s, Rr[3] * k2s, Ri[3] * k2s, 0.f);
  }
}

__device__ __forceinline__ float recon(const float4& Ra, const float4& Rb,
                                       const float* yy) {
  float S = Ra.x;
  S = fmaf(Ra.y,  yy[0], S); S = fmaf(-Ra.z, yy[1], S);
  S = fmaf(Ra.w,  yy[2], S); S = fmaf(-Rb.x, yy[3], S);
  S = fmaf(Rb.y,  yy[4], S); S = fmaf(-Rb.z, yy[5], S);
  return S;
}

// ---------------- K34 (cooperative): 512 blocks x 3 tiles, stream x ---------
// Phase A: maxes over this block's 3 tiles -> one atomicMax pair.
// grid.sync. Phase B: re-read x (L3-resident) + Rtab (L2), write 3 channels.
// launch_bounds(256,2): VGPR cap 256 (no spill), 2 blocks/CU co-residency.
__global__ __launch_bounds__(256, 2) void k34_fused(const float* __restrict__ x,
    const float* __restrict__ Rtab, unsigned int* __restrict__ maxes,
    float* __restrict__ out) {
  const int tid = threadIdx.x;
  const int xi = (tid & 127) * 4;
  const int p = tid >> 7;
  __shared__ float yt3[3][32][6];
  __shared__ float sm[8];

  // y-twiddle tables for the block's 3 tiles (built once, used in both phases)
  if (tid < 96) {
    const int k = tid >> 5, e = tid & 31;
    const int t = blockIdx.x * 3 + k;
    const int y = ((t & 15) << 5) + e;
    float c1, s1;
    __sincosf(TWOPI_N * (float)y, &s1, &c1);
    const float c2 = c1 * c1 - s1 * s1, s2 = 2.f * c1 * s1;
    const float c3 = c1 * c2 - s1 * s2, s3 = s1 * c2 + c1 * s2;
    yt3[k][e][0] = c1; yt3[k][e][1] = s1;
    yt3[k][e][2] = c2; yt3[k][e][3] = s2;
    yt3[k][e][4] = c3; yt3[k][e][5] = s3;
  }
  __syncthreads();

  // ---------- Phase A: maxes ----------
  float mlp = 0.f, mhp = 0.f;
  #pragma unroll
  for (int k = 0; k < 3; ++k) {
    const int t = blockIdx.x * 3 + k;
    const int img = t >> 4;
    const int ybase = (t & 15) << 5;
    const float* rt = Rtab + (size_t)(img * 512 + xi) * 8;
    float4 Ra[4], Rb[4];
    #pragma unroll
    for (int j = 0; j < 4; ++j) {
      Ra[j] = *reinterpret_cast<const float4*>(rt + j * 8);
      Rb[j] = *reinterpret_cast<const float4*>(rt + j * 8 + 4);
    }
    const float* xim = x + (((size_t)img) << 18);
    for (int it = 0; it < 16; ++it) {
      const int yy = it * 2 + p;
      const int y = ybase + yy;
      float yv[6];
      #pragma unroll
      for (int q = 0; q < 6; ++q) yv[q] = yt3[k][yy][q];
      const float4 xv = *reinterpret_cast<const float4*>(xim + y * NN + xi);
      const float xe[4] = {xv.x, xv.y, xv.z, xv.w};
      #pragma unroll
      for (int j = 0; j < 4; ++j) {
        const float sig = recon(Ra[j], Rb[j], yv);
        mlp = fmaxf(mlp, fabsf(sig));
        mhp = fmaxf(mhp, fabsf(xe[j] - sig));
      }
    }
  }
  #pragma unroll
  for (int off = 32; off; off >>= 1) {
    mlp = fmaxf(mlp, __shfl_down(mlp, off));
    mhp = fmaxf(mhp, __shfl_down(mhp, off));
  }
  const int lane = tid & 63, wv = tid >> 6;
  if (lane == 0) { sm[wv * 2] = mlp; sm[wv * 2 + 1] = mhp; }
  __syncthreads();
  if (tid == 0) {
    const float a  = fmaxf(fmaxf(sm[0], sm[2]), fmaxf(sm[4], sm[6]));
    const float bb = fmaxf(fmaxf(sm[1], sm[3]), fmaxf(sm[5], sm[7]));
    atomicMax(&maxes[0], __float_as_uint(a));   // nonneg floats: bit order == value order
    atomicMax(&maxes[1], __float_as_uint(bb));
  }
  __threadfence();
  cooperative_groups::this_grid().sync();

  // ---------- Phase B: normalized write ----------
  const float inv_lp = 1.f / __uint_as_float(
      __hip_atomic_load(&maxes[0], __ATOMIC_RELAXED, __HIP_MEMORY_SCOPE_AGENT));
  const float inv_hp = 1.f / __uint_as_float(
      __hip_atomic_load(&maxes[1], __ATOMIC_RELAXED, __HIP_MEMORY_SCOPE_AGENT));
  #pragma unroll
  for (int k = 0; k < 3; ++k) {
    const int t = blockIdx.x * 3 + k;
    const int img = t >> 4;
    const int b = img / 3, c = img - b * 3;
    const int ybase = (t & 15) << 5;
    const float* rt = Rtab + (size_t)(img * 512 + xi) * 8;
    float4 Ra[4], Rb[4];
    #pragma unroll
    for (int j = 0; j < 4; ++j) {
      Ra[j] = *reinterpret_cast<const float4*>(rt + j * 8);
      Rb[j] = *reinterpret_cast<const float4*>(rt + j * 8 + 4);
    }
    const float* xim = x + (((size_t)img) << 18);
    float* o0 = out + (((size_t)(b * 9 + c)) << 18);
    float* o1 = out + (((size_t)(b * 9 + 3 + c)) << 18);
    float* o2 = out + (((size_t)(b * 9 + 6 + c)) << 18);
    for (int it = 0; it < 16; ++it) {
      const int yy = it * 2 + p;
      const int y = ybase + yy;
      float yv[6];
      #pragma unroll
      for (int q = 0; q < 6; ++q) yv[q] = yt3[k][yy][q];
      const float4 xv = *reinterpret_cast<const float4*>(xim + y * NN + xi);
      const float xe[4] = {xv.x, xv.y, xv.z, xv.w};
      f4v lpv, hpv, xvv;
      #pragma unroll
      for (int j = 0; j < 4; ++j) {
        const float sig = recon(Ra[j], Rb[j], yv);
        lpv[j] = fabsf(sig) * inv_lp;
        hpv[j] = fabsf(xe[j] - sig) * inv_hp;
        xvv[j] = xe[j];
      }
      const int o = y * NN + xi;
      __builtin_nontemporal_store(xvv, reinterpret_cast<f4v*>(o0 + o));
      __builtin_nontemporal_store(lpv, reinterpret_cast<f4v*>(o1 + o));
      __builtin_nontemporal_store(hpv, reinterpret_cast<f4v*>(o2 + o));
    }
  }
}

// ---------------- fallback pair (used only if cooperative launch fails) -----
__device__ __forceinline__ void load_ctx(const float* __restrict__ Rtab, int img,
                                         int xi, int ybase, int tid,
                                         float (*yt)[6], float4 Ra[4], float4 Rb[4]) {
  if (tid < 32) {
    const int y = ybase + tid;
    float c1, s1;
    __sincosf(TWOPI_N * (float)y, &s1, &c1);
    const float c2 = c1 * c1 - s1 * s1, s2 = 2.f * c1 * s1;
    const float c3 = c1 * c2 - s1 * s2, s3 = s1 * c2 + c1 * s2;
    yt[tid][0] = c1; yt[tid][1] = s1;
    yt[tid][2] = c2; yt[tid][3] = s2;
    yt[tid][4] = c3; yt[tid][5] = s3;
  }
  const float* rt = Rtab + (size_t)(img * 512 + xi) * 8;
  #pragma unroll
  for (int j = 0; j < 4; ++j) {
    Ra[j] = *reinterpret_cast<const float4*>(rt + j * 8);
    Rb[j] = *reinterpret_cast<const float4*>(rt + j * 8 + 4);
  }
  __syncthreads();
}

__global__ __launch_bounds__(256) void k3_maxes(const float* __restrict__ x,
    const float* __restrict__ Rtab, unsigned int* __restrict__ maxes) {
  const int img = blockIdx.y;
  const int tid = threadIdx.x;
  const int xi = (tid & 127) * 4;
  const int p = tid >> 7;
  const int ybase = blockIdx.x * 32;
  __shared__ float yt[32][6];
  float4 Ra[4], Rb[4];
  load_ctx(Rtab, img, xi, ybase, tid, yt, Ra, Rb);
  const float* xim = x + (((size_t)img) << 18);
  float mlp = 0.f, mhp = 0.f;
  for (int it = 0; it < 16; ++it) {
    const int yy = it * 2 + p;
    const int y = ybase + yy;
    float yv[6];
    #pragma unroll
    for (int q = 0; q < 6; ++q) yv[q] = yt[yy][q];
    const float4 xv = *reinterpret_cast<const float4*>(xim + y * NN + xi);
    const float xe[4] = {xv.x, xv.y, xv.z, xv.w};
    #pragma unroll
    for (int j = 0; j < 4; ++j) {
      const float sig = recon(Ra[j], Rb[j], yv);
      mlp = fmaxf(mlp, fabsf(sig));
      mhp = fmaxf(mhp, fabsf(xe[j] - sig));
    }
  }
  #pragma unroll
  for (int off = 32; off; off >>= 1) {
    mlp = fmaxf(mlp, __shfl_down(mlp, off));
    mhp = fmaxf(mhp, __shfl_down(mhp, off));
  }
  __shared__ float sm[8];
  const int lane = tid & 63, wv = tid >> 6;
  if (lane == 0) { sm[wv * 2] = mlp; sm[wv * 2 + 1] = mhp; }
  __syncthreads();
  if (tid == 0) {
    const float a  = fmaxf(fmaxf(sm[0], sm[2]), fmaxf(sm[4], sm[6]));
    const float bb = fmaxf(fmaxf(sm[1], sm[3]), fmaxf(sm[5], sm[7]));
    atomicMax(&maxes[0], __float_as_uint(a));
    atomicMax(&maxes[1], __float_as_uint(bb));
  }
}

__global__ __launch_bounds__(256) void k4_write(const float* __restrict__ x,
    const float* __restrict__ Rtab, const unsigned int* __restrict__ maxes,
    float* __restrict__ out) {
  const int img = blockIdx.y;
  const int b = img / 3, c = img - b * 3;
  const int tid = threadIdx.x;
  const int xi = (tid & 127) * 4;
  const int p = tid >> 7;
  const int ybase = blockIdx.x * 32;
  __shared__ float yt[32][6];
  float4 Ra[4], Rb[4];
  load_ctx(Rtab, img, xi, ybase, tid, yt, Ra, Rb);
  const float inv_lp = 1.f / __uint_as_float(maxes[0]);
  const float inv_hp = 1.f / __uint_as_float(maxes[1]);
  const float* xim = x + (((size_t)img) << 18);
  float* o0 = out + (((size_t)(b * 9 + c)) << 18);
  float* o1 = out + (((size_t)(b * 9 + 3 + c)) << 18);
  float* o2 = out + (((size_t)(b * 9 + 6 + c)) << 18);
  for (int it = 0; it < 16; ++it) {
    const int yy = it * 2 + p;
    const int y = ybase + yy;
    float yv[6];
    #pragma unroll
    for (int q = 0; q < 6; ++q) yv[q] = yt[yy][q];
    const float4 xv = *reinterpret_cast<const float4*>(xim + y * NN + xi);
    const float xe[4] = {xv.x, xv.y, xv.z, xv.w};
    f4v lpv, hpv, xvv;
    #pragma unroll
    for (int j = 0; j < 4; ++j) {
      const float sig = recon(Ra[j], Rb[j], yv);
      lpv[j] = fabsf(sig) * inv_lp;
      hpv[j] = fabsf(xe[j] - sig) * inv_hp;
      xvv[j] = xe[j];
    }
    const int o = y * NN + xi;
    __builtin_nontemporal_store(xvv, reinterpret_cast<f4v*>(o0 + o));
    __builtin_nontemporal_store(lpv, reinterpret_cast<f4v*>(o1 + o));
    __builtin_nontemporal_store(hpv, reinterpret_cast<f4v*>(o2 + o));
  }
}

extern "C" void kernel_launch(void* const* d_in, const int* in_sizes, int n_in,
                              void* d_out, int out_size, void* d_ws, size_t ws_size,
                              hipStream_t stream) {
  if (ws_size < (size_t)WS_NEEDED) return;  // loud failure instead of corruption
  const float* x = (const float*)d_in[0];
  float* out = (float*)d_out;
  char* ws = (char*)d_ws;
  float* G = (float*)(ws + G_OFF);
  float* Rtab = (float*)(ws + R_OFF);
  unsigned int* maxes = (unsigned int*)(ws + MAX_OFF);

  k1_rowfft<<<dim3(32, IMGS), 256, 0, stream>>>(x, G, maxes);
  k2_colfft<<<dim3(IMGS), 256, 0, stream>>>(G, Rtab);

  void* args[] = {(void*)&x, (void*)&Rtab, (void*)&maxes, (void*)&out};
  hipError_t e = hipLaunchCooperativeKernel((const void*)k34_fused,
                                            dim3(512), dim3(256),
                                            args, 0, stream);
  if (e != hipSuccess) {
    // fallback: proven two-kernel path (same numerics)
    k3_maxes<<<dim3(16, IMGS), 256, 0, stream>>>(x, Rtab, maxes);
    k4_write<<<dim3(16, IMGS), 256, 0, stream>>>(x, Rtab, maxes, out);
  }
}

// Round 6
// 146.799 us; speedup vs baseline: 3.2621x; 1.3853x over previous
//
#include <hip/hip_runtime.h>

// FeatureExtractor: out = concat([x, |ifft2(low)|/max, |ifft2(high)|/max], axis=1)
// x: (32,3,512,512) fp32. Mask keeps 45 freq bins (|ky|,|kx|<=3, ky^2+kx^2<16).
// Low-pass signal s is REAL (symmetric mask, real input); hp = |x - s|.
// Pipeline (split, full-occupancy each phase — coop grid.sync refuted in R5):
//   K1 row-DFT -> K2 col-DFT + per-x table Rtab
//   K3 maxes + channel-0 x-copy (uses the x read it must do anyway)
//   K4 normalized lp/hp write.
// R6 A/B: plain stores everywhere (NT removed) vs R2's 149.8 us NT baseline.

#define NN 512
#define IMGS 96
constexpr float TWOPI_N = 6.2831853071795864769f / 512.0f;
constexpr float INV_N2  = 1.0f / (512.0f * 512.0f);

// workspace layout (bytes)
#define G_OFF   0                              // 96*512*8 floats = 1,572,864 B
#define R_OFF   (96 * 512 * 8 * 4)             // Rtab: 96*512*8 floats = 1,572,864 B
#define MAX_OFF (R_OFF + 96 * 512 * 8 * 4)     // 2 uints
#define WS_NEEDED (MAX_OFF + 8)

// ---------------- K1: per-row DFT at kx=0..3 (4 rows/wave, 16 lanes/row) ----
__global__ __launch_bounds__(256) void k1_rowfft(const float* __restrict__ x,
                                                 float* __restrict__ G,
                                                 unsigned int* __restrict__ maxes) {
  const int tid = threadIdx.x;
  if (blockIdx.x == 0 && blockIdx.y == 0 && tid == 0) {
    maxes[0] = 0u; maxes[1] = 0u;   // fold memset into K1 (K3 runs later in stream)
  }
  const int img = blockIdx.y;
  const int row = blockIdx.x * 16 + ((tid >> 6) << 2) + ((tid & 63) >> 4);
  const int l16 = tid & 15;
  const float* xr = x + (((size_t)img) << 18) + row * NN;

  float gr0 = 0.f, gr1 = 0.f, gi1 = 0.f, gr2 = 0.f, gi2 = 0.f, gr3 = 0.f, gi3 = 0.f;
  const float cd  = 0.99992470183914454f;    // cos(2pi/512)
  const float sd  = 0.012271538285719925f;   // sin(2pi/512)
  const float r45 = 0.70710678118654752f;    // cos(pi/4) = sin(pi/4), EXACT rotation/iter
  float c, s;
  __sincosf(TWOPI_N * (float)(l16 * 4), &s, &c);
  #pragma unroll
  for (int it = 0; it < 8; ++it) {
    const float4 xv = *reinterpret_cast<const float4*>(xr + it * 64 + l16 * 4);
    const float xe[4] = {xv.x, xv.y, xv.z, xv.w};
    float cc = c, ss = s;
    #pragma unroll
    for (int j = 0; j < 4; ++j) {
      const float c2 = cc * cc - ss * ss, s2 = 2.f * cc * ss;
      const float c3 = cc * c2 - ss * s2, s3 = ss * c2 + cc * s2;
      const float xx = xe[j];
      gr0 += xx;
      gr1 = fmaf(xx, cc, gr1);  gi1 = fmaf(-xx, ss, gi1);   // e^{-i*1*theta}
      gr2 = fmaf(xx, c2, gr2);  gi2 = fmaf(-xx, s2, gi2);
      gr3 = fmaf(xx, c3, gr3);  gi3 = fmaf(-xx, s3, gi3);
      const float cn = cc * cd - ss * sd;
      const float sn = ss * cd + cc * sd;
      cc = cn; ss = sn;
    }
    const float cN = r45 * (c - s);   // advance base by 64 columns = pi/4, exact
    const float sN = r45 * (c + s);
    c = cN; s = sN;
  }
  #pragma unroll
  for (int off = 8; off; off >>= 1) {
    gr0 += __shfl_down(gr0, off);
    gr1 += __shfl_down(gr1, off); gi1 += __shfl_down(gi1, off);
    gr2 += __shfl_down(gr2, off); gi2 += __shfl_down(gi2, off);
    gr3 += __shfl_down(gr3, off); gi3 += __shfl_down(gi3, off);
  }
  if (l16 == 0) {
    float* g = G + (size_t)(img * 512 + row) * 8;
    *reinterpret_cast<float4*>(g)     = make_float4(gr0, 0.f, gr1, gi1);
    *reinterpret_cast<float4*>(g + 4) = make_float4(gr2, gi2, gr3, gi3);
  }
}

// ---------------- K2: column DFT G -> F (LDS) -> per-x table Rtab ------------
__global__ __launch_bounds__(256) void k2_colfft(const float* __restrict__ G,
                                                 float* __restrict__ Rtab) {
  const int img = blockIdx.x;
  const int tid = threadIdx.x;
  float Fr[28], Fi[28];
  #pragma unroll
  for (int f = 0; f < 28; ++f) { Fr[f] = 0.f; Fi[f] = 0.f; }

  #pragma unroll
  for (int half = 0; half < 2; ++half) {
    const int u = half * 256 + tid;
    const float* g = G + (size_t)(img * 512 + u) * 8;
    const float4 ga = *reinterpret_cast<const float4*>(g);
    const float4 gb = *reinterpret_cast<const float4*>(g + 4);
    const float Gr[4] = {ga.x, ga.z, gb.x, gb.z};
    const float Gi[4] = {0.f,  ga.w, gb.y, gb.w};
    float cu, su;
    __sincosf(TWOPI_N * (float)u, &su, &cu);
    float pc[4], ps[4];
    pc[0] = 1.f; ps[0] = 0.f;
    pc[1] = cu;  ps[1] = su;
    pc[2] = cu * cu - su * su; ps[2] = 2.f * cu * su;
    pc[3] = pc[1] * pc[2] - ps[1] * ps[2];
    ps[3] = ps[1] * pc[2] + pc[1] * ps[2];
    #pragma unroll
    for (int ky = 0; ky < 4; ++ky) {
      const float c = pc[ky], s = ps[ky];   // e^{-i ky u th} = (c, -s)
      #pragma unroll
      for (int kxs = 0; kxs < 7; ++kxs) {
        const int a = (kxs < 3) ? (3 - kxs) : (kxs - 3);
        const float gr = Gr[a];
        const float gi = (kxs < 3) ? -Gi[a] : Gi[a];   // G[u,-k] = conj(G[u,k])
        const int f = ky * 7 + kxs;
        Fr[f] += gr * c + gi * s;
        Fi[f] += gi * c - gr * s;
      }
    }
  }
  __shared__ float sm[4][56];
  __shared__ float Ff[56];
  const int lane = tid & 63;
  const int wv = tid >> 6;
  #pragma unroll
  for (int f = 0; f < 28; ++f) {
    float fr = Fr[f], fi = Fi[f];
    #pragma unroll
    for (int off = 32; off; off >>= 1) {
      fr += __shfl_down(fr, off);
      fi += __shfl_down(fi, off);
    }
    if (lane == 0) { sm[wv][f * 2] = fr; sm[wv][f * 2 + 1] = fi; }
  }
  __syncthreads();
  if (tid < 56) {
    Ff[tid] = sm[0][tid] + sm[1][tid] + sm[2][tid] + sm[3][tid];
  }
  __syncthreads();

  // per-x table: Rtab[x][8] = (R0, 2R1r, 2R1i, 2R2r, 2R2i, 2R3r, 2R3i, 0)/N^2
  float fr[28], fi[28];
  #pragma unroll
  for (int f = 0; f < 28; ++f) { fr[f] = Ff[2 * f]; fi[f] = Ff[2 * f + 1]; }
  #pragma unroll
  for (int half = 0; half < 2; ++half) {
    const int xx = half * 256 + tid;
    float c1, s1;
    __sincosf(TWOPI_N * (float)xx, &s1, &c1);
    const float c2 = c1 * c1 - s1 * s1, s2 = 2.f * c1 * s1;
    const float c3 = c1 * c2 - s1 * s2, s3 = s1 * c2 + c1 * s2;
    const float pc[4] = {1.f, c1, c2, c3};
    const float ps[4] = {0.f, s1, s2, s3};
    float Rr[4], Ri[4];
    #pragma unroll
    for (int ky = 0; ky < 4; ++ky) {
      float rr = 0.f, ri = 0.f;
      #pragma unroll
      for (int kxs = 0; kxs < 7; ++kxs) {
        if (ky == 3 && (kxs == 0 || kxs == 6)) continue;  // 9+9 >= 16 excluded
        const int a = (kxs < 3) ? (3 - kxs) : (kxs - 3);
        const float ec = pc[a];
        const float es = (kxs < 3) ? -ps[a] : ps[a];      // e^{+i kx x th}
        const int f = ky * 7 + kxs;
        rr += fr[f] * ec - fi[f] * es;
        ri += fr[f] * es + fi[f] * ec;
      }
      Rr[ky] = rr; Ri[ky] = ri;
    }
    float* o = Rtab + (size_t)(img * 512 + xx) * 8;
    const float k2s = 2.f * INV_N2;
    *reinterpret_cast<float4*>(o) =
        make_float4(Rr[0] * INV_N2, Rr[1] * k2s, Ri[1] * k2s, Rr[2] * k2s);
    *reinterpret_cast<float4*>(o + 4) =
        make_float4(Ri[2] * k2s, Rr[3] * k2s, Ri[3] * k2s, 0.f);
  }
}

// ---------------- shared per-block prologue for K3/K4 ----------------
__device__ __forceinline__ void load_ctx(const float* __restrict__ Rtab, int img,
                                         int xi, int ybase, int tid,
                                         float (*yt)[6], float4 Ra[4], float4 Rb[4]) {
  if (tid < 32) {
    const int y = ybase + tid;
    float c1, s1;
    __sincosf(TWOPI_N * (float)y, &s1, &c1);
    const float c2 = c1 * c1 - s1 * s1, s2 = 2.f * c1 * s1;
    const float c3 = c1 * c2 - s1 * s2, s3 = s1 * c2 + c1 * s2;
    yt[tid][0] = c1; yt[tid][1] = s1;
    yt[tid][2] = c2; yt[tid][3] = s2;
    yt[tid][4] = c3; yt[tid][5] = s3;
  }
  const float* rt = Rtab + (size_t)(img * 512 + xi) * 8;
  #pragma unroll
  for (int j = 0; j < 4; ++j) {
    Ra[j] = *reinterpret_cast<const float4*>(rt + j * 8);
    Rb[j] = *reinterpret_cast<const float4*>(rt + j * 8 + 4);
  }
  __syncthreads();
}

__device__ __forceinline__ float recon(const float4& Ra, const float4& Rb,
                                       const float* yy) {
  float S = Ra.x;
  S = fmaf(Ra.y,  yy[0], S); S = fmaf(-Ra.z, yy[1], S);
  S = fmaf(Ra.w,  yy[2], S); S = fmaf(-Rb.x, yy[3], S);
  S = fmaf(Rb.y,  yy[4], S); S = fmaf(-Rb.z, yy[5], S);
  return S;
}

// ---------------- K3: global maxes + channel-0 x-copy ----------------
__global__ __launch_bounds__(256) void k3_maxcopy(const float* __restrict__ x,
    const float* __restrict__ Rtab, unsigned int* __restrict__ maxes,
    float* __restrict__ out) {
  const int img = blockIdx.y;
  const int b = img / 3, c = img - b * 3;
  const int tid = threadIdx.x;
  const int xi = (tid & 127) * 4;
  const int p = tid >> 7;
  const int ybase = blockIdx.x * 32;
  __shared__ float yt[32][6];
  float4 Ra[4], Rb[4];
  load_ctx(Rtab, img, xi, ybase, tid, yt, Ra, Rb);
  const float* xim = x + (((size_t)img) << 18);
  float* o0 = out + (((size_t)(b * 9 + c)) << 18);
  float mlp = 0.f, mhp = 0.f;
  for (int it = 0; it < 16; ++it) {
    const int yy = it * 2 + p;
    const int y = ybase + yy;
    float yv[6];
    #pragma unroll
    for (int q = 0; q < 6; ++q) yv[q] = yt[yy][q];
    const float4 xv = *reinterpret_cast<const float4*>(xim + y * NN + xi);
    *reinterpret_cast<float4*>(o0 + y * NN + xi) = xv;   // channel-0 copy
    const float xe[4] = {xv.x, xv.y, xv.z, xv.w};
    #pragma unroll
    for (int j = 0; j < 4; ++j) {
      const float sig = recon(Ra[j], Rb[j], yv);
      mlp = fmaxf(mlp, fabsf(sig));
      mhp = fmaxf(mhp, fabsf(xe[j] - sig));
    }
  }
  #pragma unroll
  for (int off = 32; off; off >>= 1) {
    mlp = fmaxf(mlp, __shfl_down(mlp, off));
    mhp = fmaxf(mhp, __shfl_down(mhp, off));
  }
  __shared__ float sm[8];
  const int lane = tid & 63, wv = tid >> 6;
  if (lane == 0) { sm[wv * 2] = mlp; sm[wv * 2 + 1] = mhp; }
  __syncthreads();
  if (tid == 0) {
    const float a  = fmaxf(fmaxf(sm[0], sm[2]), fmaxf(sm[4], sm[6]));
    const float bb = fmaxf(fmaxf(sm[1], sm[3]), fmaxf(sm[5], sm[7]));
    atomicMax(&maxes[0], __float_as_uint(a));   // nonneg floats: bit order == value order
    atomicMax(&maxes[1], __float_as_uint(bb));
  }
}

// ---------------- K4: normalized lp/hp write ----------------
__global__ __launch_bounds__(256) void k4_write(const float* __restrict__ x,
    const float* __restrict__ Rtab, const unsigned int* __restrict__ maxes,
    float* __restrict__ out) {
  const int img = blockIdx.y;
  const int b = img / 3, c = img - b * 3;
  const int tid = threadIdx.x;
  const int xi = (tid & 127) * 4;
  const int p = tid >> 7;
  const int ybase = blockIdx.x * 32;
  __shared__ float yt[32][6];
  float4 Ra[4], Rb[4];
  load_ctx(Rtab, img, xi, ybase, tid, yt, Ra, Rb);
  const float inv_lp = 1.f / __uint_as_float(maxes[0]);
  const float inv_hp = 1.f / __uint_as_float(maxes[1]);
  const float* xim = x + (((size_t)img) << 18);
  float* o1 = out + (((size_t)(b * 9 + 3 + c)) << 18);
  float* o2 = out + (((size_t)(b * 9 + 6 + c)) << 18);
  for (int it = 0; it < 16; ++it) {
    const int yy = it * 2 + p;
    const int y = ybase + yy;
    float yv[6];
    #pragma unroll
    for (int q = 0; q < 6; ++q) yv[q] = yt[yy][q];
    const float4 xv = *reinterpret_cast<const float4*>(xim + y * NN + xi);
    const float xe[4] = {xv.x, xv.y, xv.z, xv.w};
    float4 lpv, hpv;
    float* lpa = &lpv.x;
    float* hpa = &hpv.x;
    #pragma unroll
    for (int j = 0; j < 4; ++j) {
      const float sig = recon(Ra[j], Rb[j], yv);
      lpa[j] = fabsf(sig) * inv_lp;
      hpa[j] = fabsf(xe[j] - sig) * inv_hp;
    }
    const int o = y * NN + xi;
    *reinterpret_cast<float4*>(o1 + o) = lpv;
    *reinterpret_cast<float4*>(o2 + o) = hpv;
  }
}

extern "C" void kernel_launch(void* const* d_in, const int* in_sizes, int n_in,
                              void* d_out, int out_size, void* d_ws, size_t ws_size,
                              hipStream_t stream) {
  if (ws_size < (size_t)WS_NEEDED) return;  // loud failure instead of corruption
  const float* x = (const float*)d_in[0];
  float* out = (float*)d_out;
  char* ws = (char*)d_ws;
  float* G = (float*)(ws + G_OFF);
  float* Rtab = (float*)(ws + R_OFF);
  unsigned int* maxes = (unsigned int*)(ws + MAX_OFF);

  k1_rowfft<<<dim3(32, IMGS), 256, 0, stream>>>(x, G, maxes);
  k2_colfft<<<dim3(IMGS), 256, 0, stream>>>(G, Rtab);
  k3_maxcopy<<<dim3(16, IMGS), 256, 0, stream>>>(x, Rtab, maxes, out);
  k4_write<<<dim3(16, IMGS), 256, 0, stream>>>(x, Rtab, maxes, out);
}